// Round 1
// baseline (60.416 us; speedup 1.0000x reference)
//
#include <hip/hip_runtime.h>
#include <hip/hip_bf16.h>

// Problem constants from reference setup_inputs(): B=256, D=512, fp32.
#define BB 256
#define DD 512
#define NCHUNK 8              // row chunks in phase 1
#define ROWS_PER_CHUNK (BB / NCHUNK)   // 32

// Phase 1: per-column (per-d) partial sums over a 32-row chunk.
// Stats per d: A = sum(exp(lv) + mu^2), P = sum(exp(-lv)),
//              M = sum(mu), Q = sum(mu*exp(-lv)), R = sum(mu^2*exp(-lv))
// ws layout: ws[chunk][stat(5)][DD] floats  -> 8*5*512*4 = 80 KB
__global__ void udl_phase1(const float* __restrict__ mu,
                           const float* __restrict__ lv,
                           float* __restrict__ ws) {
    const int d = threadIdx.x;        // 0..511
    const int chunk = blockIdx.x;     // 0..7
    const int row0 = chunk * ROWS_PER_CHUNK;

    float A = 0.f, P = 0.f, M = 0.f, Q = 0.f, R = 0.f;
#pragma unroll 4
    for (int r = 0; r < ROWS_PER_CHUNK; ++r) {
        const int idx = (row0 + r) * DD + d;   // coalesced: contiguous across threads
        const float m = mu[idx];
        const float l = lv[idx];
        const float ev = __expf(l);
        const float iv = __expf(-l);
        A += ev + m * m;
        P += iv;
        M += m;
        const float miv = m * iv;
        Q += miv;
        R += m * miv;
    }
    float* o = ws + (size_t)chunk * 5 * DD;
    o[0 * DD + d] = A;
    o[1 * DD + d] = P;
    o[2 * DD + d] = M;
    o[3 * DD + d] = Q;
    o[4 * DD + d] = R;
}

// Phase 2: combine chunk partials per d, form c[d] = A*P - 2*M*Q + B*R,
// block-reduce over d (double), apply closed form, write scalar.
__global__ void udl_phase2(const float* __restrict__ ws,
                           float* __restrict__ out) {
    const int d = threadIdx.x;        // 512 threads, one per column
    float A = 0.f, P = 0.f, M = 0.f, Q = 0.f, R = 0.f;
#pragma unroll
    for (int c = 0; c < NCHUNK; ++c) {
        const float* o = ws + (size_t)c * 5 * DD;
        A += o[0 * DD + d];
        P += o[1 * DD + d];
        M += o[2 * DD + d];
        Q += o[3 * DD + d];
        R += o[4 * DD + d];
    }
    double cd = (double)A * (double)P
              - 2.0 * (double)M * (double)Q
              + (double)BB * (double)R;

    // wave (64-lane) shuffle reduce, then LDS across the 8 waves
    for (int off = 32; off > 0; off >>= 1)
        cd += __shfl_down(cd, off, 64);

    __shared__ double sred[DD / 64];
    const int wid = threadIdx.x >> 6;
    const int lane = threadIdx.x & 63;
    if (lane == 0) sred[wid] = cd;
    __syncthreads();

    if (threadIdx.x == 0) {
        double full = 0.0;
#pragma unroll
        for (int w = 0; w < DD / 64; ++w) full += sred[w];
        // answer = (Full - D*B^2) / (2B)
        const double result = (full - (double)DD * (double)BB * (double)BB)
                              / (2.0 * (double)BB);
        out[0] = (float)result;
    }
}

extern "C" void kernel_launch(void* const* d_in, const int* in_sizes, int n_in,
                              void* d_out, int out_size, void* d_ws, size_t ws_size,
                              hipStream_t stream) {
    const float* mu = (const float*)d_in[0];
    const float* lv = (const float*)d_in[1];
    float* out = (float*)d_out;
    float* ws = (float*)d_ws;

    udl_phase1<<<NCHUNK, DD, 0, stream>>>(mu, lv, ws);
    udl_phase2<<<1, DD, 0, stream>>>(ws, out);
}